// Round 7
// baseline (61.106 us; speedup 1.0000x reference)
//
#include <hip/hip_runtime.h>
#include <hip/hip_bf16.h>
#include <math.h>

#define HEADS 8
#define DH 32
#define DIM 256
#define INNER 256
#define B_ 2
#define S_ 8
#define H_ 32
#define W_ 16
#define NTOK (B_*S_*H_*W_)   /* 8192 */

// padded halo: 15 real runs (3 ds x 5 hh) of 24 (hw 0..23) + 1 pad run = 384
#define RUNLEN 24
#define NHE 384
#define NQKT_H 12            /* QK tiles per half-wave (192/16) */
#define NCH_H  6             /* PV chunks per half-wave (192/32) */

// vT padded pitch: VTOFF chosen so PV group bases are 8-token (16B) aligned:
// tb = 16m + off - 2 + VTOFF with off in {0,8,16}  ->  VTOFF=10 gives tb%8==0.
#define VTPITCH (NTOK + 24)
#define VTOFF 10

typedef _Float16 h16;
typedef h16 half8 __attribute__((ext_vector_type(8)));
typedef float f32x4 __attribute__((ext_vector_type(4)));

// ---------------------------------------------------------------------------
// MFMA f16 GEMM (HW-validated R3/R4). OUT_MODE: 0=f32 row, 1=f16 row,
// 2=f16 transposed (out[col*VTPITCH + VTOFF + row]).
// ---------------------------------------------------------------------------
#define GBM 128
#define GBN 64
#define GBK 32
#define GPITCH 40

__device__ __forceinline__ uint4 cvt8(const float4 a, const float4 b) {
    union { h16 h[8]; uint4 u; } p;
    p.h[0] = (h16)a.x; p.h[1] = (h16)a.y; p.h[2] = (h16)a.z; p.h[3] = (h16)a.w;
    p.h[4] = (h16)b.x; p.h[5] = (h16)b.y; p.h[6] = (h16)b.z; p.h[7] = (h16)b.w;
    return p.u;
}

template <bool A_F16, int OUT_MODE>
__device__ __forceinline__ void mfma_gemm_tile_t(
    const void* __restrict__ Av, const float* __restrict__ W,
    const float* __restrict__ bias, void* __restrict__ outv,
    int m0, int j0, h16* aT, h16* bT)
{
    const int tid  = threadIdx.x;
    const int lane = tid & 63;
    const int wid  = tid >> 6;
    const int wr   = wid >> 1;
    const int wc   = wid & 1;
    const int r    = lane & 15;
    const int g    = lane >> 4;

    f32x4 acc[4][2];
    #pragma unroll
    for (int i = 0; i < 4; ++i)
        #pragma unroll
        for (int j = 0; j < 2; ++j)
            acc[i][j] = (f32x4){0.f, 0.f, 0.f, 0.f};

    const int arow  = tid >> 1;
    const int ahalf = (tid & 1) * 16;
    const int brow  = (tid & 127) >> 1;
    const bool doB  = tid < 128;

    for (int k0 = 0; k0 < DIM; k0 += GBK) {
        if constexpr (A_F16) {
            const h16* A = (const h16*)Av;
            const h16* src = A + (size_t)(m0 + arow) * DIM + k0 + ahalf;
            *(uint4*)(aT + arow * GPITCH + ahalf + 0) = *(const uint4*)(src + 0);
            *(uint4*)(aT + arow * GPITCH + ahalf + 8) = *(const uint4*)(src + 8);
        } else {
            const float* A = (const float*)Av;
            const float* src = A + (size_t)(m0 + arow) * DIM + k0 + ahalf;
            const float4 u0 = *(const float4*)(src + 0);
            const float4 u1 = *(const float4*)(src + 4);
            const float4 u2 = *(const float4*)(src + 8);
            const float4 u3 = *(const float4*)(src + 12);
            *(uint4*)(aT + arow * GPITCH + ahalf + 0) = cvt8(u0, u1);
            *(uint4*)(aT + arow * GPITCH + ahalf + 8) = cvt8(u2, u3);
        }
        if (doB) {
            const float* src = W + (size_t)(j0 + brow) * DIM + k0 + ahalf;
            const float4 u0 = *(const float4*)(src + 0);
            const float4 u1 = *(const float4*)(src + 4);
            const float4 u2 = *(const float4*)(src + 8);
            const float4 u3 = *(const float4*)(src + 12);
            *(uint4*)(bT + brow * GPITCH + ahalf + 0) = cvt8(u0, u1);
            *(uint4*)(bT + brow * GPITCH + ahalf + 8) = cvt8(u2, u3);
        }
        __syncthreads();

        half8 af[4], bf[2];
        #pragma unroll
        for (int fr = 0; fr < 4; ++fr)
            af[fr] = *(const half8*)(aT + (wr * 64 + fr * 16 + r) * GPITCH + g * 8);
        #pragma unroll
        for (int fc = 0; fc < 2; ++fc)
            bf[fc] = *(const half8*)(bT + (wc * 32 + fc * 16 + r) * GPITCH + g * 8);

        #pragma unroll
        for (int fr = 0; fr < 4; ++fr)
            #pragma unroll
            for (int fc = 0; fc < 2; ++fc)
                acc[fr][fc] = __builtin_amdgcn_mfma_f32_16x16x32_f16(
                    af[fr], bf[fc], acc[fr][fc], 0, 0, 0);
        __syncthreads();
    }

    #pragma unroll
    for (int fr = 0; fr < 4; ++fr) {
        #pragma unroll
        for (int fc = 0; fc < 2; ++fc) {
            const int col = j0 + wc * 32 + fc * 16 + r;
            const float badd = bias ? bias[col] : 0.f;
            if constexpr (OUT_MODE == 2) {
                // transposed f16: out[col][VTOFF+row]; base byte % 8 == 4 ->
                // two 4B stores.
                const int rowb = m0 + wr * 64 + fr * 16 + g * 4;
                union { h16 h[4]; uint u[2]; } p;
                #pragma unroll
                for (int i = 0; i < 4; ++i) p.h[i] = (h16)(acc[fr][fc][i] + badd);
                h16* dst = (h16*)outv + (size_t)col * VTPITCH + VTOFF + rowb;
                *(uint*)(dst + 0) = p.u[0];
                *(uint*)(dst + 2) = p.u[1];
            } else {
                #pragma unroll
                for (int i = 0; i < 4; ++i) {
                    const int row = m0 + wr * 64 + fr * 16 + g * 4 + i;
                    const float val = acc[fr][fc][i] + badd;
                    if constexpr (OUT_MODE == 1)
                        ((h16*)outv)[(size_t)row * INNER + col] = (h16)val;
                    else
                        ((float*)outv)[(size_t)row * INNER + col] = val;
                }
            }
        }
    }
}

// ---------------------------------------------------------------------------
// Kernel 1: projections. q,k -> row-major f16 [2][NTOK][INNER]; v -> vT f16
// [INNER][VTPITCH] (data at +VTOFF).
// ---------------------------------------------------------------------------
__global__ __launch_bounds__(256) void proj_kernel(
    const float* __restrict__ x, const float* __restrict__ q,
    const float* __restrict__ wq, const float* __restrict__ wk,
    const float* __restrict__ wv, h16* __restrict__ qk, h16* __restrict__ vT)
{
    __shared__ h16 aT[GBM * GPITCH];
    __shared__ h16 bT[GBN * GPITCH];

    const int seg = blockIdx.y >> 2;
    const int jt  = blockIdx.y & 3;
    const float* A = (seg == 0) ? q : x;
    const float* W = (seg == 0) ? wq : ((seg == 1) ? wk : wv);

    if (seg == 2) {
        mfma_gemm_tile_t<false, 2>(A, W, nullptr, vT, blockIdx.x * GBM, jt * GBN, aT, bT);
    } else {
        h16* outp = qk + (size_t)seg * NTOK * INNER;
        mfma_gemm_tile_t<false, 1>(A, W, nullptr, outp, blockIdx.x * GBM, jt * GBN, aT, bT);
    }
}

// ---------------------------------------------------------------------------
// Kernel 2: MFMA local attention, halo split across 2 waves per (row, head).
// grid = (512 rows, 4 head-pairs), 256 thr = 4 waves.
// wave wid: head = hp*2 + (wid>>1), half = wid&1 (halo runs 0-7 / 8-15).
// Each wave: partial (m, s, O) over 192 entries; merge via LDS.
// ---------------------------------------------------------------------------
__global__ __launch_bounds__(256, 8) void attn_kernel(
    const h16* __restrict__ qk, const h16* __restrict__ vT, h16* __restrict__ ao)
{
    __shared__ int   nn_lds[NHE];
    __shared__ int   tb48[48];
    __shared__ float ms[4][2][16];      /* [wid][m,s][q] */
    __shared__ float obuf[2][64][9];    /* half=1 partial O, padded */

    const int r_raw = blockIdx.x;
    const int r     = ((r_raw & 7) << 6) | (r_raw >> 3);   // XCD swizzle
    const int hp    = blockIdx.y;
    const int tid   = threadIdx.x;
    const int lane  = tid & 63;
    const int wid   = tid >> 6;
    const int hl    = wid >> 1;          // head_local 0..1
    const int half  = wid & 1;
    const int head  = hp * 2 + hl;

    const int h = r & 31, s = (r >> 5) & 7, b = r >> 8;
    const int n_base = r * 16;

    // ---- halo table: ent = nn | hw<<16 | inb<<24 --------------------------
    for (int ht = tid; ht < NHE; ht += 256) {
        const int run = ht / RUNLEN;          // 0..15 (15 = pad)
        const int hw  = ht - run * RUNLEN;    // 0..23
        const int ds  = run / 5;
        const int hh  = run - ds * 5;
        const int s2 = s + ds - 1, h2 = h + hh - 2, w2 = hw - 2;
        const bool inb = (run < 15) && ((unsigned)s2 < 8u) &&
                         ((unsigned)h2 < 32u) && ((unsigned)w2 < 16u);
        const int s2c = min(max(s2, 0), 7);
        const int h2c = min(max(h2, 0), 31);
        const int w2c = min(max(w2, 0), 15);
        const int nn  = ((b * 8 + s2c) * 32 + h2c) * 16 + w2c;
        nn_lds[ht] = nn | (hw << 16) | (inb ? (1 << 24) : 0);
    }
    // ---- per-8-group V base position in PADDED vT coords (16B aligned) ----
    if (tid < 48) {
        const int k0  = tid * 8;
        const int run = k0 / RUNLEN;
        const int off = k0 - run * RUNLEN;    // 0, 8, 16
        const int ds  = run / 5;
        const int hh  = run - ds * 5;
        const int s2c = min(max(s + ds - 1, 0), 7);
        const int h2c = min(max(h + hh - 2, 0), 31);
        tb48[tid] = ((b * 8 + s2c) * 32 + h2c) * 16 + off - 2 + VTOFF;  // %8==0
    }
    __syncthreads();

    const int c = lane & 15;
    const int g = lane >> 4;
    const int E0 = half * 192;

    const h16* kb = qk + (size_t)NTOK * INNER;   // K segment
    const half8 qf = *(const half8*)(qk + (size_t)(n_base + c) * INNER + head * DH + g * 8);

    // ---- QK (swapped): dots[t][i] = S[q=c][halo=E0+16t+4g+i] --------------
    f32x4 dots[NQKT_H];
    #pragma unroll
    for (int t = 0; t < NQKT_H; ++t) {
        const int ent = nn_lds[E0 + 16 * t + c];
        const half8 kf = *(const half8*)(kb + (size_t)(ent & 0xffff) * INNER + head * DH + g * 8);
        dots[t] = __builtin_amdgcn_mfma_f32_16x16x32_f16(kf, qf, (f32x4){0.f,0.f,0.f,0.f}, 0, 0, 0);
    }

    // ---- mask + max -------------------------------------------------------
    float mx = -1e30f;
    #pragma unroll
    for (int t = 0; t < NQKT_H; ++t) {
        #pragma unroll
        for (int i = 0; i < 4; ++i) {
            const int ent = nn_lds[E0 + 16 * t + 4 * g + i];
            const int hw  = (ent >> 16) & 255;
            const bool ok = (ent >> 24) && ((unsigned)(hw - c) <= 4u);
            const float dv = ok ? dots[t][i] : -1e30f;
            dots[t][i] = dv;
            mx = fmaxf(mx, dv);
        }
    }
    mx = fmaxf(mx, __shfl_xor(mx, 16));
    mx = fmaxf(mx, __shfl_xor(mx, 32));

    // ---- exp + sum (unnormalized) ----------------------------------------
    const float scale = 0.17677669529663687f;   // 32^-0.5
    float sum = 0.f;
    #pragma unroll
    for (int t = 0; t < NQKT_H; ++t)
        #pragma unroll
        for (int i = 0; i < 4; ++i) {
            const float e = __expf((dots[t][i] - mx) * scale);
            dots[t][i] = e;
            sum += e;
        }
    sum += __shfl_xor(sum, 16);
    sum += __shfl_xor(sum, 32);

    if (lane < 16) {                    // per-q partial stats (q = lane)
        ms[wid][0][lane] = mx;
        ms[wid][1][lane] = sum;
    }

    // ---- pack unnormalized P to f16 dword pairs ---------------------------
    int d0[NQKT_H], d1[NQKT_H];
    #pragma unroll
    for (int t = 0; t < NQKT_H; ++t) {
        union { h16 hh2[2]; int u; } p0, p1;
        p0.hh2[0] = (h16)dots[t][0]; p0.hh2[1] = (h16)dots[t][1];
        p1.hh2[0] = (h16)dots[t][2]; p1.hh2[1] = (h16)dots[t][3];
        d0[t] = p0.u; d1[t] = p1.u;
    }

    // ---- PV: 6 chunks; A-frag via shfl, B-frag via aligned b128 gather ----
    f32x4 o0 = (f32x4){0.f,0.f,0.f,0.f};
    f32x4 o1 = (f32x4){0.f,0.f,0.f,0.f};
    const bool hi = lane >= 32;
    const int l1 = ((lane & 16) ? 32 : 0) + c;
    const int l2 = l1 + 16;

    #pragma unroll
    for (int ch = 0; ch < NCH_H; ++ch) {
        const int w0a = __shfl(d0[2*ch], l1), w0b = __shfl(d0[2*ch+1], l1);
        const int w1a = __shfl(d1[2*ch], l1), w1b = __shfl(d1[2*ch+1], l1);
        const int w2a = __shfl(d0[2*ch], l2), w2b = __shfl(d0[2*ch+1], l2);
        const int w3a = __shfl(d1[2*ch], l2), w3b = __shfl(d1[2*ch+1], l2);
        union { int u[4]; half8 hv; } pf;
        pf.u[0] = hi ? w0b : w0a;
        pf.u[1] = hi ? w1b : w1a;
        pf.u[2] = hi ? w2b : w2a;
        pf.u[3] = hi ? w3b : w3a;

        const int tb = tb48[half * 24 + ch * 4 + g];   // 16B-aligned base
        union { uint4 u4; half8 hv; } v0f, v1f;
        v0f.u4 = *(const uint4*)(vT + (size_t)(head * DH + c) * VTPITCH + tb);
        v1f.u4 = *(const uint4*)(vT + (size_t)(head * DH + 16 + c) * VTPITCH + tb);

        o0 = __builtin_amdgcn_mfma_f32_16x16x32_f16(pf.hv, v0f.hv, o0, 0, 0, 0);
        o1 = __builtin_amdgcn_mfma_f32_16x16x32_f16(pf.hv, v1f.hv, o1, 0, 0, 0);
    }

    // ---- publish half=1 partials, merge in half=0, write ------------------
    if (half == 1) {
        #pragma unroll
        for (int i = 0; i < 4; ++i) {
            obuf[hl][lane][i]     = o0[i];
            obuf[hl][lane][4 + i] = o1[i];
        }
    }
    __syncthreads();

    if (half == 0) {
        #pragma unroll
        for (int i = 0; i < 4; ++i) {
            const int qi = 4 * g + i;
            const float m_a = ms[wid][0][qi],     s_a = ms[wid][1][qi];
            const float m_b = ms[wid | 1][0][qi], s_b = ms[wid | 1][1][qi];
            const float m  = fmaxf(m_a, m_b);
            const float ea = __expf((m_a - m) * scale);
            const float eb = __expf((m_b - m) * scale);
            const float den = 1.f / (s_a * ea + s_b * eb);
            const float ob0 = obuf[hl][lane][i];
            const float ob1 = obuf[hl][lane][4 + i];
            const float r0 = (o0[i] * ea + ob0 * eb) * den;
            const float r1 = (o1[i] * ea + ob1 * eb) * den;
            const size_t row = (size_t)(n_base + qi) * INNER + head * DH;
            ao[row + c]      = (h16)r0;
            ao[row + 16 + c] = (h16)r1;
        }
    }
}

// ---------------------------------------------------------------------------
// Kernel 3: out = ao(f16) @ wo^T + bo   grid = (64, 4)
// ---------------------------------------------------------------------------
__global__ __launch_bounds__(256) void outproj_kernel(
    const h16* __restrict__ ao, const float* __restrict__ wo,
    const float* __restrict__ bo, float* __restrict__ out)
{
    __shared__ h16 aT[GBM * GPITCH];
    __shared__ h16 bT[GBN * GPITCH];
    mfma_gemm_tile_t<true, 0>(ao, wo, bo, out, blockIdx.x * GBM, blockIdx.y * GBN, aT, bT);
}

// ---------------------------------------------------------------------------
extern "C" void kernel_launch(void* const* d_in, const int* in_sizes, int n_in,
                              void* d_out, int out_size, void* d_ws, size_t ws_size,
                              hipStream_t stream) {
    const float* x  = (const float*)d_in[0];
    const float* q  = (const float*)d_in[1];
    const float* wq = (const float*)d_in[2];
    const float* wk = (const float*)d_in[3];
    const float* wv = (const float*)d_in[4];
    const float* wo = (const float*)d_in[5];
    const float* bo = (const float*)d_in[6];
    float* out = (float*)d_out;

    // ws: qk f16 [2][NTOK][INNER] (8MB) + vT f16 [INNER][VTPITCH] (4.2MB) + ao (4MB)
    h16* qk = (h16*)d_ws;
    h16* vT = qk + (size_t)2 * NTOK * INNER;
    h16* ao = vT + (size_t)INNER * VTPITCH;

    dim3 g1(NTOK / GBM, 12);
    proj_kernel<<<g1, 256, 0, stream>>>(x, q, wq, wk, wv, qk, vT);

    dim3 g2(NTOK / W_, 4);
    attn_kernel<<<g2, 256, 0, stream>>>(qk, vT, ao);

    dim3 g3(NTOK / GBM, INNER / GBN);
    outproj_kernel<<<g3, 256, 0, stream>>>(ao, wo, bo, out);
}

// Round 8
// 53.730 us; speedup vs baseline: 1.1373x; 1.1373x over previous
//
#include <hip/hip_runtime.h>
#include <hip/hip_bf16.h>
#include <math.h>

#define HEADS 8
#define DH 32
#define DIM 256
#define INNER 256
#define B_ 2
#define S_ 8
#define H_ 32
#define W_ 16
#define NTOK (B_*S_*H_*W_)   /* 8192 */

// padded halo: 15 real runs (3 ds x 5 hh) of 24 (hw 0..23) + 1 pad run = 384
#define RUNLEN 24
#define NHE 384
#define NQKT_H 12            /* QK tiles per half-wave (192/16) */
#define NCH_H  6             /* PV chunks per half-wave (192/32) */

// vT padded pitch: VTOFF chosen so PV group bases are 8-token (16B) aligned:
// tb = 16m + off - 2 + VTOFF with off in {0,8,16}  ->  VTOFF=10 gives tb%8==0.
#define VTPITCH (NTOK + 24)
#define VTOFF 10

typedef _Float16 h16;
typedef h16 half8 __attribute__((ext_vector_type(8)));
typedef float f32x4 __attribute__((ext_vector_type(4)));

// ---------------------------------------------------------------------------
// MFMA f16 GEMM (HW-validated R3/R4). OUT_MODE: 0=f32 row, 1=f16 row,
// 2=f16 transposed (out[col*VTPITCH + VTOFF + row]).
// ---------------------------------------------------------------------------
#define GBM 128
#define GBN 64
#define GBK 32
#define GPITCH 40

__device__ __forceinline__ uint4 cvt8(const float4 a, const float4 b) {
    union { h16 h[8]; uint4 u; } p;
    p.h[0] = (h16)a.x; p.h[1] = (h16)a.y; p.h[2] = (h16)a.z; p.h[3] = (h16)a.w;
    p.h[4] = (h16)b.x; p.h[5] = (h16)b.y; p.h[6] = (h16)b.z; p.h[7] = (h16)b.w;
    return p.u;
}

template <bool A_F16, int OUT_MODE>
__device__ __forceinline__ void mfma_gemm_tile_t(
    const void* __restrict__ Av, const float* __restrict__ W,
    const float* __restrict__ bias, void* __restrict__ outv,
    int m0, int j0, h16* aT, h16* bT)
{
    const int tid  = threadIdx.x;
    const int lane = tid & 63;
    const int wid  = tid >> 6;
    const int wr   = wid >> 1;
    const int wc   = wid & 1;
    const int r    = lane & 15;
    const int g    = lane >> 4;

    f32x4 acc[4][2];
    #pragma unroll
    for (int i = 0; i < 4; ++i)
        #pragma unroll
        for (int j = 0; j < 2; ++j)
            acc[i][j] = (f32x4){0.f, 0.f, 0.f, 0.f};

    const int arow  = tid >> 1;
    const int ahalf = (tid & 1) * 16;
    const int brow  = (tid & 127) >> 1;
    const bool doB  = tid < 128;

    for (int k0 = 0; k0 < DIM; k0 += GBK) {
        if constexpr (A_F16) {
            const h16* A = (const h16*)Av;
            const h16* src = A + (size_t)(m0 + arow) * DIM + k0 + ahalf;
            *(uint4*)(aT + arow * GPITCH + ahalf + 0) = *(const uint4*)(src + 0);
            *(uint4*)(aT + arow * GPITCH + ahalf + 8) = *(const uint4*)(src + 8);
        } else {
            const float* A = (const float*)Av;
            const float* src = A + (size_t)(m0 + arow) * DIM + k0 + ahalf;
            const float4 u0 = *(const float4*)(src + 0);
            const float4 u1 = *(const float4*)(src + 4);
            const float4 u2 = *(const float4*)(src + 8);
            const float4 u3 = *(const float4*)(src + 12);
            *(uint4*)(aT + arow * GPITCH + ahalf + 0) = cvt8(u0, u1);
            *(uint4*)(aT + arow * GPITCH + ahalf + 8) = cvt8(u2, u3);
        }
        if (doB) {
            const float* src = W + (size_t)(j0 + brow) * DIM + k0 + ahalf;
            const float4 u0 = *(const float4*)(src + 0);
            const float4 u1 = *(const float4*)(src + 4);
            const float4 u2 = *(const float4*)(src + 8);
            const float4 u3 = *(const float4*)(src + 12);
            *(uint4*)(bT + brow * GPITCH + ahalf + 0) = cvt8(u0, u1);
            *(uint4*)(bT + brow * GPITCH + ahalf + 8) = cvt8(u2, u3);
        }
        __syncthreads();

        half8 af[4], bf[2];
        #pragma unroll
        for (int fr = 0; fr < 4; ++fr)
            af[fr] = *(const half8*)(aT + (wr * 64 + fr * 16 + r) * GPITCH + g * 8);
        #pragma unroll
        for (int fc = 0; fc < 2; ++fc)
            bf[fc] = *(const half8*)(bT + (wc * 32 + fc * 16 + r) * GPITCH + g * 8);

        #pragma unroll
        for (int fr = 0; fr < 4; ++fr)
            #pragma unroll
            for (int fc = 0; fc < 2; ++fc)
                acc[fr][fc] = __builtin_amdgcn_mfma_f32_16x16x32_f16(
                    af[fr], bf[fc], acc[fr][fc], 0, 0, 0);
        __syncthreads();
    }

    #pragma unroll
    for (int fr = 0; fr < 4; ++fr) {
        #pragma unroll
        for (int fc = 0; fc < 2; ++fc) {
            const int col = j0 + wc * 32 + fc * 16 + r;
            const float badd = bias ? bias[col] : 0.f;
            if constexpr (OUT_MODE == 2) {
                // transposed f16: out[col][VTOFF+row]; base byte % 8 == 4 ->
                // two 4B stores.
                const int rowb = m0 + wr * 64 + fr * 16 + g * 4;
                union { h16 h[4]; uint u[2]; } p;
                #pragma unroll
                for (int i = 0; i < 4; ++i) p.h[i] = (h16)(acc[fr][fc][i] + badd);
                h16* dst = (h16*)outv + (size_t)col * VTPITCH + VTOFF + rowb;
                *(uint*)(dst + 0) = p.u[0];
                *(uint*)(dst + 2) = p.u[1];
            } else {
                #pragma unroll
                for (int i = 0; i < 4; ++i) {
                    const int row = m0 + wr * 64 + fr * 16 + g * 4 + i;
                    const float val = acc[fr][fc][i] + badd;
                    if constexpr (OUT_MODE == 1)
                        ((h16*)outv)[(size_t)row * INNER + col] = (h16)val;
                    else
                        ((float*)outv)[(size_t)row * INNER + col] = val;
                }
            }
        }
    }
}

// ---------------------------------------------------------------------------
// Kernel 1: projections. q,k -> row-major f16 [2][NTOK][INNER]; v -> vT f16
// [INNER][VTPITCH] (data at +VTOFF).
// ---------------------------------------------------------------------------
__global__ __launch_bounds__(256) void proj_kernel(
    const float* __restrict__ x, const float* __restrict__ q,
    const float* __restrict__ wq, const float* __restrict__ wk,
    const float* __restrict__ wv, h16* __restrict__ qk, h16* __restrict__ vT)
{
    __shared__ h16 aT[GBM * GPITCH];
    __shared__ h16 bT[GBN * GPITCH];

    const int seg = blockIdx.y >> 2;
    const int jt  = blockIdx.y & 3;
    const float* A = (seg == 0) ? q : x;
    const float* W = (seg == 0) ? wq : ((seg == 1) ? wk : wv);

    if (seg == 2) {
        mfma_gemm_tile_t<false, 2>(A, W, nullptr, vT, blockIdx.x * GBM, jt * GBN, aT, bT);
    } else {
        h16* outp = qk + (size_t)seg * NTOK * INNER;
        mfma_gemm_tile_t<false, 1>(A, W, nullptr, outp, blockIdx.x * GBM, jt * GBN, aT, bT);
    }
}

// ---------------------------------------------------------------------------
// Kernel 2: MFMA local attention, halo split across 2 waves per (row, head).
// grid = (512 rows, 4 head-pairs), 256 thr = 4 waves.
// wave wid: head = hp*2 + (wid>>1), half = wid&1 (halo runs 0-7 / 8-15).
// launch_bounds(256,4): VGPR cap 128 — dots + prefetched V stay in regs
// (R7's ,8 forced VGPR=32 -> scratch spills, FETCH +25MB, no speedup).
// ---------------------------------------------------------------------------
__global__ __launch_bounds__(256, 4) void attn_kernel(
    const h16* __restrict__ qk, const h16* __restrict__ vT, h16* __restrict__ ao)
{
    __shared__ int   nn_lds[NHE];
    __shared__ int   tb48[48];
    __shared__ float ms[4][2][16];      /* [wid][m,s][q] */
    __shared__ float obuf[2][64][9];    /* half=1 partial O, padded */

    const int r_raw = blockIdx.x;
    const int r     = ((r_raw & 7) << 6) | (r_raw >> 3);   // XCD swizzle
    const int hp    = blockIdx.y;
    const int tid   = threadIdx.x;
    const int lane  = tid & 63;
    const int wid   = tid >> 6;
    const int hl    = wid >> 1;          // head_local 0..1
    const int half  = wid & 1;
    const int head  = hp * 2 + hl;

    const int h = r & 31, s = (r >> 5) & 7, b = r >> 8;
    const int n_base = r * 16;

    // ---- halo table: ent = nn | hw<<16 | inb<<24 --------------------------
    for (int ht = tid; ht < NHE; ht += 256) {
        const int run = ht / RUNLEN;          // 0..15 (15 = pad)
        const int hw  = ht - run * RUNLEN;    // 0..23
        const int ds  = run / 5;
        const int hh  = run - ds * 5;
        const int s2 = s + ds - 1, h2 = h + hh - 2, w2 = hw - 2;
        const bool inb = (run < 15) && ((unsigned)s2 < 8u) &&
                         ((unsigned)h2 < 32u) && ((unsigned)w2 < 16u);
        const int s2c = min(max(s2, 0), 7);
        const int h2c = min(max(h2, 0), 31);
        const int w2c = min(max(w2, 0), 15);
        const int nn  = ((b * 8 + s2c) * 32 + h2c) * 16 + w2c;
        nn_lds[ht] = nn | (hw << 16) | (inb ? (1 << 24) : 0);
    }
    // ---- per-8-group V base position in PADDED vT coords (16B aligned) ----
    if (tid < 48) {
        const int k0  = tid * 8;
        const int run = k0 / RUNLEN;
        const int off = k0 - run * RUNLEN;    // 0, 8, 16
        const int ds  = run / 5;
        const int hh  = run - ds * 5;
        const int s2c = min(max(s + ds - 1, 0), 7);
        const int h2c = min(max(h + hh - 2, 0), 31);
        tb48[tid] = ((b * 8 + s2c) * 32 + h2c) * 16 + off - 2 + VTOFF;  // %8==0
    }
    __syncthreads();

    const int c = lane & 15;
    const int g = lane >> 4;
    const int E0 = half * 192;

    const h16* kb = qk + (size_t)NTOK * INNER;   // K segment
    const half8 qf = *(const half8*)(qk + (size_t)(n_base + c) * INNER + head * DH + g * 8);

    // ---- QK (swapped): dots[t][i] = S[q=c][halo=E0+16t+4g+i] --------------
    f32x4 dots[NQKT_H];
    #pragma unroll
    for (int t = 0; t < NQKT_H; ++t) {
        const int ent = nn_lds[E0 + 16 * t + c];
        const half8 kf = *(const half8*)(kb + (size_t)(ent & 0xffff) * INNER + head * DH + g * 8);
        dots[t] = __builtin_amdgcn_mfma_f32_16x16x32_f16(kf, qf, (f32x4){0.f,0.f,0.f,0.f}, 0, 0, 0);
    }

    // ---- prefetch all V fragments (latency hides under softmax) -----------
    union { uint4 u4; half8 hv; } vpre0[NCH_H], vpre1[NCH_H];
    #pragma unroll
    for (int ch = 0; ch < NCH_H; ++ch) {
        const int tb = tb48[half * 24 + ch * 4 + g];   // 16B-aligned base
        vpre0[ch].u4 = *(const uint4*)(vT + (size_t)(head * DH + c) * VTPITCH + tb);
        vpre1[ch].u4 = *(const uint4*)(vT + (size_t)(head * DH + 16 + c) * VTPITCH + tb);
    }

    // ---- mask + max -------------------------------------------------------
    float mx = -1e30f;
    #pragma unroll
    for (int t = 0; t < NQKT_H; ++t) {
        #pragma unroll
        for (int i = 0; i < 4; ++i) {
            const int ent = nn_lds[E0 + 16 * t + 4 * g + i];
            const int hw  = (ent >> 16) & 255;
            const bool ok = (ent >> 24) && ((unsigned)(hw - c) <= 4u);
            const float dv = ok ? dots[t][i] : -1e30f;
            dots[t][i] = dv;
            mx = fmaxf(mx, dv);
        }
    }
    mx = fmaxf(mx, __shfl_xor(mx, 16));
    mx = fmaxf(mx, __shfl_xor(mx, 32));

    // ---- exp + sum (unnormalized) ----------------------------------------
    const float scale = 0.17677669529663687f;   // 32^-0.5
    float sum = 0.f;
    #pragma unroll
    for (int t = 0; t < NQKT_H; ++t)
        #pragma unroll
        for (int i = 0; i < 4; ++i) {
            const float e = __expf((dots[t][i] - mx) * scale);
            dots[t][i] = e;
            sum += e;
        }
    sum += __shfl_xor(sum, 16);
    sum += __shfl_xor(sum, 32);

    if (lane < 16) {                    // per-q partial stats (q = lane)
        ms[wid][0][lane] = mx;
        ms[wid][1][lane] = sum;
    }

    // ---- pack unnormalized P to f16 dword pairs ---------------------------
    int d0[NQKT_H], d1[NQKT_H];
    #pragma unroll
    for (int t = 0; t < NQKT_H; ++t) {
        union { h16 hh2[2]; int u; } p0, p1;
        p0.hh2[0] = (h16)dots[t][0]; p0.hh2[1] = (h16)dots[t][1];
        p1.hh2[0] = (h16)dots[t][2]; p1.hh2[1] = (h16)dots[t][3];
        d0[t] = p0.u; d1[t] = p1.u;
    }

    // ---- PV: 6 chunks; A-frag via shfl, B-frag prefetched -----------------
    f32x4 o0 = (f32x4){0.f,0.f,0.f,0.f};
    f32x4 o1 = (f32x4){0.f,0.f,0.f,0.f};
    const bool hi = lane >= 32;
    const int l1 = ((lane & 16) ? 32 : 0) + c;
    const int l2 = l1 + 16;

    #pragma unroll
    for (int ch = 0; ch < NCH_H; ++ch) {
        const int w0a = __shfl(d0[2*ch], l1), w0b = __shfl(d0[2*ch+1], l1);
        const int w1a = __shfl(d1[2*ch], l1), w1b = __shfl(d1[2*ch+1], l1);
        const int w2a = __shfl(d0[2*ch], l2), w2b = __shfl(d0[2*ch+1], l2);
        const int w3a = __shfl(d1[2*ch], l2), w3b = __shfl(d1[2*ch+1], l2);
        union { int u[4]; half8 hv; } pf;
        pf.u[0] = hi ? w0b : w0a;
        pf.u[1] = hi ? w1b : w1a;
        pf.u[2] = hi ? w2b : w2a;
        pf.u[3] = hi ? w3b : w3a;

        o0 = __builtin_amdgcn_mfma_f32_16x16x32_f16(pf.hv, vpre0[ch].hv, o0, 0, 0, 0);
        o1 = __builtin_amdgcn_mfma_f32_16x16x32_f16(pf.hv, vpre1[ch].hv, o1, 0, 0, 0);
    }

    // ---- publish half=1 partials, merge in half=0, write ------------------
    if (half == 1) {
        #pragma unroll
        for (int i = 0; i < 4; ++i) {
            obuf[hl][lane][i]     = o0[i];
            obuf[hl][lane][4 + i] = o1[i];
        }
    }
    __syncthreads();

    if (half == 0) {
        #pragma unroll
        for (int i = 0; i < 4; ++i) {
            const int qi = 4 * g + i;
            const float m_a = ms[wid][0][qi],     s_a = ms[wid][1][qi];
            const float m_b = ms[wid | 1][0][qi], s_b = ms[wid | 1][1][qi];
            const float m  = fmaxf(m_a, m_b);
            const float ea = __expf((m_a - m) * scale);
            const float eb = __expf((m_b - m) * scale);
            const float den = 1.f / (s_a * ea + s_b * eb);
            const float ob0 = obuf[hl][lane][i];
            const float ob1 = obuf[hl][lane][4 + i];
            const float r0 = (o0[i] * ea + ob0 * eb) * den;
            const float r1 = (o1[i] * ea + ob1 * eb) * den;
            const size_t row = (size_t)(n_base + qi) * INNER + head * DH;
            ao[row + c]      = (h16)r0;
            ao[row + 16 + c] = (h16)r1;
        }
    }
}

// ---------------------------------------------------------------------------
// Kernel 3: out = ao(f16) @ wo^T + bo   grid = (64, 4)
// ---------------------------------------------------------------------------
__global__ __launch_bounds__(256) void outproj_kernel(
    const h16* __restrict__ ao, const float* __restrict__ wo,
    const float* __restrict__ bo, float* __restrict__ out)
{
    __shared__ h16 aT[GBM * GPITCH];
    __shared__ h16 bT[GBN * GPITCH];
    mfma_gemm_tile_t<true, 0>(ao, wo, bo, out, blockIdx.x * GBM, blockIdx.y * GBN, aT, bT);
}

// ---------------------------------------------------------------------------
extern "C" void kernel_launch(void* const* d_in, const int* in_sizes, int n_in,
                              void* d_out, int out_size, void* d_ws, size_t ws_size,
                              hipStream_t stream) {
    const float* x  = (const float*)d_in[0];
    const float* q  = (const float*)d_in[1];
    const float* wq = (const float*)d_in[2];
    const float* wk = (const float*)d_in[3];
    const float* wv = (const float*)d_in[4];
    const float* wo = (const float*)d_in[5];
    const float* bo = (const float*)d_in[6];
    float* out = (float*)d_out;

    // ws: qk f16 [2][NTOK][INNER] (8MB) + vT f16 [INNER][VTPITCH] (4.2MB) + ao (4MB)
    h16* qk = (h16*)d_ws;
    h16* vT = qk + (size_t)2 * NTOK * INNER;
    h16* ao = vT + (size_t)INNER * VTPITCH;

    dim3 g1(NTOK / GBM, 12);
    proj_kernel<<<g1, 256, 0, stream>>>(x, q, wq, wk, wv, qk, vT);

    dim3 g2(NTOK / W_, 4);
    attn_kernel<<<g2, 256, 0, stream>>>(qk, vT, ao);

    dim3 g3(NTOK / GBM, INNER / GBN);
    outproj_kernel<<<g3, 256, 0, stream>>>(ao, wo, bo, out);
}

// Round 9
// 49.546 us; speedup vs baseline: 1.2333x; 1.0844x over previous
//
#include <hip/hip_runtime.h>
#include <hip/hip_bf16.h>
#include <math.h>

#define HEADS 8
#define DH 32
#define DIM 256
#define INNER 256
#define B_ 2
#define S_ 8
#define H_ 32
#define W_ 16
#define NTOK (B_*S_*H_*W_)   /* 8192 */

// padded halo: 15 real runs (3 ds x 5 hh) of 24 (hw 0..23) + 1 pad run = 384
#define RUNLEN 24
#define NHE 384
#define NQKT_Q 6             /* QK tiles per quarter-wave (96/16) */
#define NCH_Q  3             /* PV chunks per quarter-wave (96/32) */

// vT padded pitch: VTOFF chosen so PV group bases are 8-token (16B) aligned:
// tb = 16m + off - 2 + VTOFF with off in {0,8,16}  ->  VTOFF=10 gives tb%8==0.
#define VTPITCH (NTOK + 24)
#define VTOFF 10

typedef _Float16 h16;
typedef h16 half8 __attribute__((ext_vector_type(8)));
typedef float f32x4 __attribute__((ext_vector_type(4)));

// ---------------------------------------------------------------------------
// MFMA f16 GEMM (HW-validated R3/R4). OUT_MODE: 0=f32 row-major,
// 2=f16 transposed (vT), 3=f16 head-major ([col>>5][row][col&31]).
// ---------------------------------------------------------------------------
#define GBM 128
#define GBN 64
#define GBK 32
#define GPITCH 40

__device__ __forceinline__ uint4 cvt8(const float4 a, const float4 b) {
    union { h16 h[8]; uint4 u; } p;
    p.h[0] = (h16)a.x; p.h[1] = (h16)a.y; p.h[2] = (h16)a.z; p.h[3] = (h16)a.w;
    p.h[4] = (h16)b.x; p.h[5] = (h16)b.y; p.h[6] = (h16)b.z; p.h[7] = (h16)b.w;
    return p.u;
}

template <bool A_F16, int OUT_MODE>
__device__ __forceinline__ void mfma_gemm_tile_t(
    const void* __restrict__ Av, const float* __restrict__ W,
    const float* __restrict__ bias, void* __restrict__ outv,
    int m0, int j0, h16* aT, h16* bT)
{
    const int tid  = threadIdx.x;
    const int lane = tid & 63;
    const int wid  = tid >> 6;
    const int wr   = wid >> 1;
    const int wc   = wid & 1;
    const int r    = lane & 15;
    const int g    = lane >> 4;

    f32x4 acc[4][2];
    #pragma unroll
    for (int i = 0; i < 4; ++i)
        #pragma unroll
        for (int j = 0; j < 2; ++j)
            acc[i][j] = (f32x4){0.f, 0.f, 0.f, 0.f};

    const int arow  = tid >> 1;
    const int ahalf = (tid & 1) * 16;
    const int brow  = (tid & 127) >> 1;
    const bool doB  = tid < 128;

    for (int k0 = 0; k0 < DIM; k0 += GBK) {
        if constexpr (A_F16) {
            const h16* A = (const h16*)Av;
            const h16* src = A + (size_t)(m0 + arow) * DIM + k0 + ahalf;
            *(uint4*)(aT + arow * GPITCH + ahalf + 0) = *(const uint4*)(src + 0);
            *(uint4*)(aT + arow * GPITCH + ahalf + 8) = *(const uint4*)(src + 8);
        } else {
            const float* A = (const float*)Av;
            const float* src = A + (size_t)(m0 + arow) * DIM + k0 + ahalf;
            const float4 u0 = *(const float4*)(src + 0);
            const float4 u1 = *(const float4*)(src + 4);
            const float4 u2 = *(const float4*)(src + 8);
            const float4 u3 = *(const float4*)(src + 12);
            *(uint4*)(aT + arow * GPITCH + ahalf + 0) = cvt8(u0, u1);
            *(uint4*)(aT + arow * GPITCH + ahalf + 8) = cvt8(u2, u3);
        }
        if (doB) {
            const float* src = W + (size_t)(j0 + brow) * DIM + k0 + ahalf;
            const float4 u0 = *(const float4*)(src + 0);
            const float4 u1 = *(const float4*)(src + 4);
            const float4 u2 = *(const float4*)(src + 8);
            const float4 u3 = *(const float4*)(src + 12);
            *(uint4*)(bT + brow * GPITCH + ahalf + 0) = cvt8(u0, u1);
            *(uint4*)(bT + brow * GPITCH + ahalf + 8) = cvt8(u2, u3);
        }
        __syncthreads();

        half8 af[4], bf[2];
        #pragma unroll
        for (int fr = 0; fr < 4; ++fr)
            af[fr] = *(const half8*)(aT + (wr * 64 + fr * 16 + r) * GPITCH + g * 8);
        #pragma unroll
        for (int fc = 0; fc < 2; ++fc)
            bf[fc] = *(const half8*)(bT + (wc * 32 + fc * 16 + r) * GPITCH + g * 8);

        #pragma unroll
        for (int fr = 0; fr < 4; ++fr)
            #pragma unroll
            for (int fc = 0; fc < 2; ++fc)
                acc[fr][fc] = __builtin_amdgcn_mfma_f32_16x16x32_f16(
                    af[fr], bf[fc], acc[fr][fc], 0, 0, 0);
        __syncthreads();
    }

    #pragma unroll
    for (int fr = 0; fr < 4; ++fr) {
        #pragma unroll
        for (int fc = 0; fc < 2; ++fc) {
            const int col = j0 + wc * 32 + fc * 16 + r;
            const float badd = bias ? bias[col] : 0.f;
            if constexpr (OUT_MODE == 2) {
                // transposed f16: out[col][VTOFF+row]; two 4B stores.
                const int rowb = m0 + wr * 64 + fr * 16 + g * 4;
                union { h16 h[4]; uint u[2]; } p;
                #pragma unroll
                for (int i = 0; i < 4; ++i) p.h[i] = (h16)(acc[fr][fc][i] + badd);
                h16* dst = (h16*)outv + (size_t)col * VTPITCH + VTOFF + rowb;
                *(uint*)(dst + 0) = p.u[0];
                *(uint*)(dst + 2) = p.u[1];
            } else if constexpr (OUT_MODE == 3) {
                // head-major f16: out[head][row][d]
                const int hd = col >> 5, d = col & 31;
                #pragma unroll
                for (int i = 0; i < 4; ++i) {
                    const int row = m0 + wr * 64 + fr * 16 + g * 4 + i;
                    ((h16*)outv)[((size_t)hd * NTOK + row) * DH + d] =
                        (h16)(acc[fr][fc][i] + badd);
                }
            } else {
                #pragma unroll
                for (int i = 0; i < 4; ++i) {
                    const int row = m0 + wr * 64 + fr * 16 + g * 4 + i;
                    ((float*)outv)[(size_t)row * INNER + col] = acc[fr][fc][i] + badd;
                }
            }
        }
    }
}

// ---------------------------------------------------------------------------
// Kernel 1: projections. q,k -> head-major f16 [2][8][NTOK][32]; v -> vT f16
// [INNER][VTPITCH] (data at +VTOFF).
// ---------------------------------------------------------------------------
__global__ __launch_bounds__(256) void proj_kernel(
    const float* __restrict__ x, const float* __restrict__ q,
    const float* __restrict__ wq, const float* __restrict__ wk,
    const float* __restrict__ wv, h16* __restrict__ qk, h16* __restrict__ vT)
{
    __shared__ h16 aT[GBM * GPITCH];
    __shared__ h16 bT[GBN * GPITCH];

    const int seg = blockIdx.y >> 2;
    const int jt  = blockIdx.y & 3;
    const float* A = (seg == 0) ? q : x;
    const float* W = (seg == 0) ? wq : ((seg == 1) ? wk : wv);

    if (seg == 2) {
        mfma_gemm_tile_t<false, 2>(A, W, nullptr, vT, blockIdx.x * GBM, jt * GBN, aT, bT);
    } else {
        h16* outp = qk + (size_t)seg * HEADS * NTOK * DH;
        mfma_gemm_tile_t<false, 3>(A, W, nullptr, outp, blockIdx.x * GBM, jt * GBN, aT, bT);
    }
}

// ---------------------------------------------------------------------------
// Kernel 2: MFMA local attention, halo split across 4 waves per (row, head).
// grid = (512 rows, 8 heads), 256 thr = 4 waves (quarter = wid, 96 entries).
// Head-major K: a QK tile's 64 lanes read one contiguous ~1KB block.
// 4-way merge via LDS. launch_bounds(256,6): VGPR cap 85 (R7 lesson: don't
// force caps below live state).
// ---------------------------------------------------------------------------
__global__ __launch_bounds__(256, 6) void attn_kernel(
    const h16* __restrict__ qk, const h16* __restrict__ vT, h16* __restrict__ ao)
{
    __shared__ int   nn_lds[NHE];
    __shared__ int   tb48[48];
    __shared__ float ms[4][2][16];      /* [quarter][m,s][q] */
    __shared__ float obuf[3][64][9];    /* quarters 1-3 partial O, padded */

    const int r_raw = blockIdx.x;
    const int r     = ((r_raw & 7) << 6) | (r_raw >> 3);   // XCD swizzle
    const int head  = blockIdx.y;
    const int tid   = threadIdx.x;
    const int lane  = tid & 63;
    const int wid   = tid >> 6;          // quarter 0..3

    const int h = r & 31, s = (r >> 5) & 7, b = r >> 8;
    const int n_base = r * 16;

    // ---- halo table: ent = nn | hw<<16 | inb<<24 --------------------------
    for (int ht = tid; ht < NHE; ht += 256) {
        const int run = ht / RUNLEN;          // 0..15 (15 = pad)
        const int hw  = ht - run * RUNLEN;    // 0..23
        const int ds  = run / 5;
        const int hh  = run - ds * 5;
        const int s2 = s + ds - 1, h2 = h + hh - 2, w2 = hw - 2;
        const bool inb = (run < 15) && ((unsigned)s2 < 8u) &&
                         ((unsigned)h2 < 32u) && ((unsigned)w2 < 16u);
        const int s2c = min(max(s2, 0), 7);
        const int h2c = min(max(h2, 0), 31);
        const int w2c = min(max(w2, 0), 15);
        const int nn  = ((b * 8 + s2c) * 32 + h2c) * 16 + w2c;
        nn_lds[ht] = nn | (hw << 16) | (inb ? (1 << 24) : 0);
    }
    // ---- per-8-group V base position in PADDED vT coords (16B aligned) ----
    if (tid < 48) {
        const int k0  = tid * 8;
        const int run = k0 / RUNLEN;
        const int off = k0 - run * RUNLEN;    // 0, 8, 16
        const int ds  = run / 5;
        const int hh  = run - ds * 5;
        const int s2c = min(max(s + ds - 1, 0), 7);
        const int h2c = min(max(h + hh - 2, 0), 31);
        tb48[tid] = ((b * 8 + s2c) * 32 + h2c) * 16 + off - 2 + VTOFF;  // %8==0
    }
    __syncthreads();

    const int c = lane & 15;
    const int g = lane >> 4;
    const int E0 = wid * 96;

    const h16* qb = qk + (size_t)head * NTOK * DH;
    const h16* kb = qk + ((size_t)(HEADS + head)) * NTOK * DH;
    const half8 qf = *(const half8*)(qb + (size_t)(n_base + c) * DH + g * 8);

    // ---- QK (swapped): dots[t][i] = S[q=c][halo=E0+16t+4g+i] --------------
    f32x4 dots[NQKT_Q];
    #pragma unroll
    for (int t = 0; t < NQKT_Q; ++t) {
        const int ent = nn_lds[E0 + 16 * t + c];
        const half8 kf = *(const half8*)(kb + (size_t)(ent & 0xffff) * DH + g * 8);
        dots[t] = __builtin_amdgcn_mfma_f32_16x16x32_f16(kf, qf, (f32x4){0.f,0.f,0.f,0.f}, 0, 0, 0);
    }

    // ---- prefetch V fragments (latency hides under softmax) ---------------
    union { uint4 u4; half8 hv; } vpre0[NCH_Q], vpre1[NCH_Q];
    #pragma unroll
    for (int ch = 0; ch < NCH_Q; ++ch) {
        const int tb = tb48[wid * 12 + ch * 4 + g];    // 16B-aligned base
        vpre0[ch].u4 = *(const uint4*)(vT + (size_t)(head * DH + c) * VTPITCH + tb);
        vpre1[ch].u4 = *(const uint4*)(vT + (size_t)(head * DH + 16 + c) * VTPITCH + tb);
    }

    // ---- mask + max -------------------------------------------------------
    float mx = -1e30f;
    #pragma unroll
    for (int t = 0; t < NQKT_Q; ++t) {
        #pragma unroll
        for (int i = 0; i < 4; ++i) {
            const int ent = nn_lds[E0 + 16 * t + 4 * g + i];
            const int hw  = (ent >> 16) & 255;
            const bool ok = (ent >> 24) && ((unsigned)(hw - c) <= 4u);
            const float dv = ok ? dots[t][i] : -1e30f;
            dots[t][i] = dv;
            mx = fmaxf(mx, dv);
        }
    }
    mx = fmaxf(mx, __shfl_xor(mx, 16));
    mx = fmaxf(mx, __shfl_xor(mx, 32));

    // ---- exp + sum (unnormalized) ----------------------------------------
    const float scale = 0.17677669529663687f;   // 32^-0.5
    float sum = 0.f;
    #pragma unroll
    for (int t = 0; t < NQKT_Q; ++t)
        #pragma unroll
        for (int i = 0; i < 4; ++i) {
            const float e = __expf((dots[t][i] - mx) * scale);
            dots[t][i] = e;
            sum += e;
        }
    sum += __shfl_xor(sum, 16);
    sum += __shfl_xor(sum, 32);

    if (lane < 16) {                    // per-q partial stats (q = lane)
        ms[wid][0][lane] = mx;
        ms[wid][1][lane] = sum;
    }

    // ---- pack unnormalized P to f16 dword pairs ---------------------------
    int d0[NQKT_Q], d1[NQKT_Q];
    #pragma unroll
    for (int t = 0; t < NQKT_Q; ++t) {
        union { h16 hh2[2]; int u; } p0, p1;
        p0.hh2[0] = (h16)dots[t][0]; p0.hh2[1] = (h16)dots[t][1];
        p1.hh2[0] = (h16)dots[t][2]; p1.hh2[1] = (h16)dots[t][3];
        d0[t] = p0.u; d1[t] = p1.u;
    }

    // ---- PV: 3 chunks; A-frag via shfl, B-frag prefetched -----------------
    f32x4 o0 = (f32x4){0.f,0.f,0.f,0.f};
    f32x4 o1 = (f32x4){0.f,0.f,0.f,0.f};
    const bool hi = lane >= 32;
    const int l1 = ((lane & 16) ? 32 : 0) + c;
    const int l2 = l1 + 16;

    #pragma unroll
    for (int ch = 0; ch < NCH_Q; ++ch) {
        const int w0a = __shfl(d0[2*ch], l1), w0b = __shfl(d0[2*ch+1], l1);
        const int w1a = __shfl(d1[2*ch], l1), w1b = __shfl(d1[2*ch+1], l1);
        const int w2a = __shfl(d0[2*ch], l2), w2b = __shfl(d0[2*ch+1], l2);
        const int w3a = __shfl(d1[2*ch], l2), w3b = __shfl(d1[2*ch+1], l2);
        union { int u[4]; half8 hv; } pf;
        pf.u[0] = hi ? w0b : w0a;
        pf.u[1] = hi ? w1b : w1a;
        pf.u[2] = hi ? w2b : w2a;
        pf.u[3] = hi ? w3b : w3a;

        o0 = __builtin_amdgcn_mfma_f32_16x16x32_f16(pf.hv, vpre0[ch].hv, o0, 0, 0, 0);
        o1 = __builtin_amdgcn_mfma_f32_16x16x32_f16(pf.hv, vpre1[ch].hv, o1, 0, 0, 0);
    }

    // ---- publish quarters 1-3, merge in quarter 0, write ------------------
    if (wid != 0) {
        #pragma unroll
        for (int i = 0; i < 4; ++i) {
            obuf[wid - 1][lane][i]     = o0[i];
            obuf[wid - 1][lane][4 + i] = o1[i];
        }
    }
    __syncthreads();

    if (wid == 0) {
        #pragma unroll
        for (int i = 0; i < 4; ++i) {
            const int qi = 4 * g + i;
            const float m0_ = ms[0][0][qi], m1_ = ms[1][0][qi];
            const float m2_ = ms[2][0][qi], m3_ = ms[3][0][qi];
            const float m = fmaxf(fmaxf(m0_, m1_), fmaxf(m2_, m3_));
            const float e0 = __expf((m0_ - m) * scale);
            const float e1 = __expf((m1_ - m) * scale);
            const float e2 = __expf((m2_ - m) * scale);
            const float e3 = __expf((m3_ - m) * scale);
            const float den = 1.f / (ms[0][1][qi] * e0 + ms[1][1][qi] * e1 +
                                     ms[2][1][qi] * e2 + ms[3][1][qi] * e3);
            const float r0 = (o0[i] * e0 + obuf[0][lane][i] * e1 +
                              obuf[1][lane][i] * e2 + obuf[2][lane][i] * e3) * den;
            const float r1 = (o1[i] * e0 + obuf[0][lane][4+i] * e1 +
                              obuf[1][lane][4+i] * e2 + obuf[2][lane][4+i] * e3) * den;
            const size_t row = (size_t)(n_base + qi) * INNER + head * DH;
            ao[row + c]      = (h16)r0;
            ao[row + 16 + c] = (h16)r1;
        }
    }
}

// ---------------------------------------------------------------------------
// Kernel 3: out = ao(f16) @ wo^T + bo   grid = (64, 4)
// ---------------------------------------------------------------------------
__global__ __launch_bounds__(256) void outproj_kernel(
    const h16* __restrict__ ao, const float* __restrict__ wo,
    const float* __restrict__ bo, float* __restrict__ out)
{
    __shared__ h16 aT[GBM * GPITCH];
    __shared__ h16 bT[GBN * GPITCH];
    mfma_gemm_tile_t<true, 0>(ao, wo, bo, out, blockIdx.x * GBM, blockIdx.y * GBN, aT, bT);
}

// ---------------------------------------------------------------------------
extern "C" void kernel_launch(void* const* d_in, const int* in_sizes, int n_in,
                              void* d_out, int out_size, void* d_ws, size_t ws_size,
                              hipStream_t stream) {
    const float* x  = (const float*)d_in[0];
    const float* q  = (const float*)d_in[1];
    const float* wq = (const float*)d_in[2];
    const float* wk = (const float*)d_in[3];
    const float* wv = (const float*)d_in[4];
    const float* wo = (const float*)d_in[5];
    const float* bo = (const float*)d_in[6];
    float* out = (float*)d_out;

    // ws: qk f16 [2][8][NTOK][32] (8MB) + vT f16 [INNER][VTPITCH] (4.2MB) + ao (4MB)
    h16* qk = (h16*)d_ws;
    h16* vT = qk + (size_t)2 * HEADS * NTOK * DH;
    h16* ao = vT + (size_t)INNER * VTPITCH;

    dim3 g1(NTOK / GBM, 12);
    proj_kernel<<<g1, 256, 0, stream>>>(x, q, wq, wk, wv, qk, vT);

    dim3 g2(NTOK / W_, HEADS);
    attn_kernel<<<g2, 256, 0, stream>>>(qk, vT, ao);

    dim3 g3(NTOK / GBM, INNER / GBN);
    outproj_kernel<<<g3, 256, 0, stream>>>(ao, wo, bo, out);
}